// Round 2
// 604.486 us; speedup vs baseline: 1.2371x; 1.2371x over previous
//
#include <hip/hip_runtime.h>

typedef __bf16 bf16_t;
typedef bf16_t bf16x4 __attribute__((ext_vector_type(4)));
typedef bf16_t bf16x8 __attribute__((ext_vector_type(8)));
typedef float floatx4 __attribute__((ext_vector_type(4)));

#define F_INq 64
#define F_OUTq 128
#define PERIODSq 12
#define XROW (F_INq * PERIODSq) /* 768 */

// ---------------- degree / CSR build ----------------
__global__ __launch_bounds__(256) void k_init(float* deg, int* counts, int N) {
  int i = blockIdx.x * 256 + threadIdx.x;
  if (i < N) { deg[i] = 1.0f; counts[i] = 0; }  // self-loop weight 1
}

__global__ __launch_bounds__(256) void k_accum(const int* __restrict__ ei, const float* __restrict__ ew,
                                               float* deg, int* counts, int E) {
  int e = blockIdx.x * 256 + threadIdx.x;
  if (e < E) {
    int c = ei[E + e];  // target
    atomicAdd(&deg[c], ew[e]);
    atomicAdd(&counts[c], 1);
  }
}

__global__ __launch_bounds__(256) void k_dinv(float* deg, int N) {
  int i = blockIdx.x * 256 + threadIdx.x;
  if (i < N) { float d = deg[i]; deg[i] = d > 0.0f ? rsqrtf(d) : 0.0f; }
}

// ---------------- multi-block scan (3 small kernels) ----------------
// A: per-1024-chunk sums
__global__ __launch_bounds__(256) void k_scanA(const int* __restrict__ counts, int* __restrict__ bsum, int N) {
  __shared__ int ws[4];
  int b = blockIdx.x, t = threadIdx.x;
  int base = b * 1024 + t * 4;
  int s = 0;
  if (base + 3 < N) {
    int4 c = *(const int4*)(counts + base);
    s = c.x + c.y + c.z + c.w;
  } else {
    for (int k = 0; k < 4; ++k) if (base + k < N) s += counts[base + k];
  }
  for (int off = 1; off < 64; off <<= 1) s += __shfl_xor(s, off);
  int lane = t & 63, w = t >> 6;
  if (lane == 0) ws[w] = s;
  __syncthreads();
  if (t == 0) bsum[b] = ws[0] + ws[1] + ws[2] + ws[3];
}

// B: exclusive scan of <=64 block sums (single wave); bbase[nb] = grand total
__global__ __launch_bounds__(64) void k_scanB(const int* __restrict__ bsum, int* __restrict__ bbase, int nb) {
  int t = threadIdx.x;
  int v = t < nb ? bsum[t] : 0;
  int inc = v;
  for (int off = 1; off < 64; off <<= 1) {
    int u = __shfl_up(inc, off);
    if (t >= off) inc += u;
  }
  if (t < nb) bbase[t] = inc - v;
  if (t == nb - 1) bbase[nb] = inc;
}

// C: per-chunk local scan + base, writes offs/cursor; offs[N] from bbase[nb]
__global__ __launch_bounds__(256) void k_scanC(const int* __restrict__ counts, const int* __restrict__ bbase,
                                               int* __restrict__ offs, int* __restrict__ cursor, int N, int nb) {
  __shared__ int ws[4];
  int b = blockIdx.x, t = threadIdx.x;
  int base = b * 1024 + t * 4;
  int c0_ = 0, c1_ = 0, c2_ = 0, c3_ = 0;
  if (base + 3 < N) {
    int4 c = *(const int4*)(counts + base);
    c0_ = c.x; c1_ = c.y; c2_ = c.z; c3_ = c.w;
  } else {
    if (base < N) c0_ = counts[base];
    if (base + 1 < N) c1_ = counts[base + 1];
    if (base + 2 < N) c2_ = counts[base + 2];
    if (base + 3 < N) c3_ = counts[base + 3];
  }
  int tot = c0_ + c1_ + c2_ + c3_;
  int lane = t & 63, w = t >> 6;
  int inc = tot;
  for (int off = 1; off < 64; off <<= 1) {
    int u = __shfl_up(inc, off);
    if (lane >= off) inc += u;
  }
  if (lane == 63) ws[w] = inc;
  __syncthreads();
  int wb = bbase[b];
  for (int i = 0; i < w; ++i) wb += ws[i];
  int e = wb + inc - tot;
  if (base < N)     { offs[base] = e;                 cursor[base] = e; }
  if (base + 1 < N) { int o = e + c0_;                offs[base + 1] = o; cursor[base + 1] = o; }
  if (base + 2 < N) { int o = e + c0_ + c1_;          offs[base + 2] = o; cursor[base + 2] = o; }
  if (base + 3 < N) { int o = e + c0_ + c1_ + c2_;    offs[base + 3] = o; cursor[base + 3] = o; }
  if (b == 0 && t == 0) offs[N] = bbase[nb];
}

// fallback single-block scan (only if nb > 64; N=40000 -> never)
__global__ __launch_bounds__(1024) void k_scan(const int* __restrict__ counts, int* __restrict__ offs,
                                               int* __restrict__ cursor, int N) {
  __shared__ int sd[1024];
  int t = threadIdx.x;
  int CH = (N + 1023) >> 10;
  int base = t * CH;
  int sum = 0;
  for (int i = 0; i < CH; ++i) { int idx = base + i; if (idx < N) sum += counts[idx]; }
  sd[t] = sum;
  __syncthreads();
  for (int off = 1; off < 1024; off <<= 1) {
    int v = (t >= off) ? sd[t - off] : 0;
    __syncthreads();
    sd[t] += v;
    __syncthreads();
  }
  int run = sd[t] - sum;  // exclusive prefix
  for (int i = 0; i < CH; ++i) {
    int idx = base + i;
    if (idx < N) { offs[idx] = run; cursor[idx] = run; run += counts[idx]; }
  }
  if (t == 1023) offs[N] = sd[1023];
}

__global__ __launch_bounds__(256) void k_scatter(const int* __restrict__ ei, const float* __restrict__ ew,
                                                 const float* __restrict__ dinv, int* cursor,
                                                 int* __restrict__ csr_src, float* __restrict__ csr_nrm, int E) {
  int e = blockIdx.x * 256 + threadIdx.x;
  if (e < E) {
    int r = ei[e], c = ei[E + e];
    int p = atomicAdd(&cursor[c], 1);
    csr_src[p] = r;
    csr_nrm[p] = dinv[r] * ew[e] * dinv[c];
  }
}

// ---------------- weight precompute: W_bigT[512][192], b_comb[512], probs[12] ----------------
__global__ __launch_bounds__(256) void k_prew(
    const float* __restrict__ Wxi, const float* __restrict__ Whi,
    const float* __restrict__ Wxf, const float* __restrict__ Whf,
    const float* __restrict__ Wxc, const float* __restrict__ Whc,
    const float* __restrict__ Wxo, const float* __restrict__ Who,
    const float* __restrict__ bxi, const float* __restrict__ bhi,
    const float* __restrict__ bxf, const float* __restrict__ bhf,
    const float* __restrict__ bxc, const float* __restrict__ bhc,
    const float* __restrict__ bxo, const float* __restrict__ bho,
    const float* __restrict__ att,
    bf16_t* __restrict__ WbT, float* __restrict__ bcomb, float* __restrict__ probs) {
  const int WT = 512 * 192;
  int gid = blockIdx.x * 256 + threadIdx.x;
  if (gid < WT) {
    int col = gid / 192, k = gid % 192;
    int g = col >> 7, j = col & 127;
    const float* Wx = g == 0 ? Wxi : g == 1 ? Wxf : g == 2 ? Wxc : Wxo;
    const float* Wh = g == 0 ? Whi : g == 1 ? Whf : g == 2 ? Whc : Who;
    float s;
    if (k < 64) {
      s = 0.0f;
      for (int kk = 0; kk < 128; ++kk) s += Wx[k * 128 + kk] * Wh[kk * 128 + j];
    } else {
      s = Wh[(k + 64) * 128 + j];
    }
    WbT[(size_t)col * 192 + k] = (bf16_t)s;
  } else if (gid < WT + 512) {
    int cc = gid - WT;
    int g = cc >> 7, j = cc & 127;
    const float* bx = g == 0 ? bxi : g == 1 ? bxf : g == 2 ? bxc : bxo;
    const float* bh = g == 0 ? bhi : g == 1 ? bhf : g == 2 ? bhc : bho;
    const float* Wh = g == 0 ? Whi : g == 1 ? Whf : g == 2 ? Whc : Who;
    float s = bh[j];
    for (int kk = 0; kk < 128; ++kk) s += bx[kk] * Wh[kk * 128 + j];
    bcomb[cc] = s;
  } else if (gid == WT + 512) {
    float m = att[0];
    for (int i = 1; i < PERIODSq; ++i) m = fmaxf(m, att[i]);
    float e[PERIODSq], s = 0.0f;
    for (int i = 0; i < PERIODSq; ++i) { e[i] = __expf(att[i] - m); s += e[i]; }
    for (int i = 0; i < PERIODSq; ++i) probs[i] = e[i] / s;
  }
}

// ---------------- X transpose/convert: X[n][f][t] fp32 -> Xb[n][t*64+f] bf16 ----------------
__global__ __launch_bounds__(192) void k_xpose(const float* __restrict__ X, bf16_t* __restrict__ Xb) {
  __shared__ float lds[XROW];
  const int n = blockIdx.x, tid = threadIdx.x;
  const float4* Xr = (const float4*)(X + (size_t)n * XROW);
  float4 v = Xr[tid];
  lds[tid * 4 + 0] = v.x;
  lds[tid * 4 + 1] = v.y;
  lds[tid * 4 + 2] = v.z;
  lds[tid * 4 + 3] = v.w;
  __syncthreads();
  const int o = tid * 4;
  bf16x4 r;
#pragma unroll
  for (int k = 0; k < 4; ++k) {
    int oo = o + k;
    int tt = oo >> 6, f = oo & 63;
    r[k] = (bf16_t)lds[f * PERIODSq + tt];
  }
  *(bf16x4*)(Xb + (size_t)n * XROW + o) = r;
}

// ---------------- aggregation (bf16 gather): Xagg[t][n][64] = A_norm @ X ----------------
__global__ __launch_bounds__(256) void k_agg2(const bf16_t* __restrict__ Xb, const int* __restrict__ csr_src,
                                              const float* __restrict__ csr_nrm, const int* __restrict__ offs,
                                              const float* __restrict__ dinv, bf16_t* __restrict__ Xagg, int N) {
  const int node = blockIdx.x * 4 + (threadIdx.x >> 6);
  const int lane = threadIdx.x & 63;
  const int s0 = offs[node], s1 = offs[node + 1];
  floatx4 a0 = {0.f, 0.f, 0.f, 0.f}, a1 = a0, a2 = a0;
  int e = s0;
  for (; e + 8 <= s1; e += 8) {
    bf16x4 v[8][3];
    float nn[8];
#pragma unroll
    for (int u = 0; u < 8; ++u) {
      int s = csr_src[e + u];
      nn[u] = csr_nrm[e + u];
      const bf16x4* xp = (const bf16x4*)(Xb + (size_t)s * XROW) + lane;
      v[u][0] = xp[0]; v[u][1] = xp[64]; v[u][2] = xp[128];
    }
#pragma unroll
    for (int u = 0; u < 8; ++u) {
#pragma unroll
      for (int k = 0; k < 4; ++k) {
        a0[k] += nn[u] * (float)v[u][0][k];
        a1[k] += nn[u] * (float)v[u][1][k];
        a2[k] += nn[u] * (float)v[u][2][k];
      }
    }
  }
  for (; e < s1; ++e) {
    int s = csr_src[e];
    float nr = csr_nrm[e];
    const bf16x4* xp = (const bf16x4*)(Xb + (size_t)s * XROW) + lane;
    bf16x4 v0 = xp[0], v1 = xp[64], v2 = xp[128];
#pragma unroll
    for (int k = 0; k < 4; ++k) {
      a0[k] += nr * (float)v0[k];
      a1[k] += nr * (float)v1[k];
      a2[k] += nr * (float)v2[k];
    }
  }
  float dc = dinv[node];
  float self = dc * dc;
  const bf16x4* xc = (const bf16x4*)(Xb + (size_t)node * XROW) + lane;
  {
    bf16x4 v0 = xc[0], v1 = xc[64], v2 = xc[128];
#pragma unroll
    for (int k = 0; k < 4; ++k) {
      a0[k] += self * (float)v0[k];
      a1[k] += self * (float)v1[k];
      a2[k] += self * (float)v2[k];
    }
  }
  const int f4 = lane & 15, tq = lane >> 4;
  floatx4 accs[3] = {a0, a1, a2};
#pragma unroll
  for (int j = 0; j < 3; ++j) {
    int tt = tq + 4 * j;
    bf16x4 r;
#pragma unroll
    for (int k = 0; k < 4; ++k) r[k] = (bf16_t)accs[j][k];
    *(bf16x4*)(Xagg + ((size_t)tt * N + node) * 64 + f4 * 4) = r;
  }
}

// ---------------- fallback aggregation (fp32 gather, used only if ws too small) ----------------
__global__ __launch_bounds__(256) void k_agg(const float* __restrict__ X, const int* __restrict__ csr_src,
                                             const float* __restrict__ csr_nrm, const int* __restrict__ offs,
                                             const float* __restrict__ dinv, bf16_t* __restrict__ Xagg, int N) {
  int c = blockIdx.x;
  int tid = threadIdx.x;
  int s0 = offs[c], s1 = offs[c + 1];
  const int i0 = tid, i1 = tid + 256, i2 = tid + 512;
  float a0 = 0.f, a1 = 0.f, a2 = 0.f;
  for (int e = s0; e < s1; ++e) {
    int s = csr_src[e];
    float nr = csr_nrm[e];
    const float* xp = X + (size_t)s * XROW;
    a0 += nr * xp[i0]; a1 += nr * xp[i1]; a2 += nr * xp[i2];
  }
  float dc = dinv[c];
  float self = dc * dc;
  const float* xc = X + (size_t)c * XROW;
  a0 += self * xc[i0]; a1 += self * xc[i1]; a2 += self * xc[i2];
  __shared__ float lds[XROW];
  lds[i0] = a0; lds[i1] = a1; lds[i2] = a2;
  __syncthreads();
  for (int o = tid; o < XROW; o += 256) {
    int tt = o >> 6, f = o & 63;
    Xagg[(size_t)tt * N * 64 + (size_t)c * 64 + f] = (bf16_t)lds[f * PERIODSq + tt];
  }
}

// ---------------- persistent fused LSTM, W-stationary ----------------
// Structure (this round, re-submit after infra failure):
//  * H double-buffered in LDS -> ONE barrier per period (was 2).
//  * 256B row pitch + XOR granule swizzle (granule ^= row&7): 16B-aligned ds_read_b128 /
//    8B ds_write_b64, exactly min accesses/bank (conflict-free).
//  * X(t+1) B-frags prefetched at TOP of period t, consumed at END of t (full-period cover).
//  * acc ping-pong: X-part MFMAs of t+1 issue during epilogue(t) -> matrix pipe busy while
//    VALU/trans run the sigmoid/tanh chain (only 2 waves/SIMD resident, so intra-wave
//    overlap is the only available overlap).
//  * bias preloaded in 16 VGPRs as MFMA C-init.
//  * period 0 skips H-part (H(-1)=0): no LDS zero-init, no initial barrier.
// VGPR est: Wf 96 + accA 32 + accB 32 + bv 16 + Cst/Ha 16 + Xf 16 + transients ~= 235 < 256 cap.
__global__ __launch_bounds__(512, 2) void k_gate_all(const bf16_t* __restrict__ Xagg,
                                                     const bf16_t* __restrict__ WbT,
                                                     const float* __restrict__ bcomb,
                                                     const float* __restrict__ probs,
                                                     float* __restrict__ out, int N) {
  __shared__ __align__(16) char Hs[2][32 * 256];
  const int tid = threadIdx.x;
  const int lane = tid & 63, w = tid >> 6;
  const int q = lane >> 4, c0 = lane & 15;
  const int n0 = blockIdx.x * 32;
  const int swz = c0 & 7;

  // stationary W fragments: col = (g*8+w)*16 + c0, k-chunk ks*32 + q*8
  bf16x8 Wf[4][6];
#pragma unroll
  for (int g = 0; g < 4; ++g) {
    const bf16_t* wp = WbT + (size_t)((g * 8 + w) * 16 + c0) * 192;
#pragma unroll
    for (int ks = 0; ks < 6; ++ks) Wf[g][ks] = *(const bf16x8*)(wp + ks * 32 + q * 8);
  }
  // bias in regs (per-thread 16 floats), used as MFMA C-init
  floatx4 bv[4];
#pragma unroll
  for (int g = 0; g < 4; ++g) bv[g] = *(const floatx4*)(bcomb + g * 128 + w * 16 + q * 4);

  floatx4 Cst[2], Ha[2];
#pragma unroll
  for (int rt = 0; rt < 2; ++rt) {
    Cst[rt] = (floatx4){0.f, 0.f, 0.f, 0.f};
    Ha[rt] = (floatx4){0.f, 0.f, 0.f, 0.f};
  }

  const bf16_t* Xrow0 = Xagg + (size_t)(n0 + c0) * 64 + q * 8;       // rt=0 node row
  const bf16_t* Xrow1 = Xagg + (size_t)(n0 + 16 + c0) * 64 + q * 8;  // rt=1 node row

  // X(0) frags + accA = bias + X-part(0)
  bf16x8 Xf0 = *(const bf16x8*)(Xrow0);
  bf16x8 Xf1 = *(const bf16x8*)(Xrow0 + 32);
  bf16x8 Xf2 = *(const bf16x8*)(Xrow1);
  bf16x8 Xf3 = *(const bf16x8*)(Xrow1 + 32);

  floatx4 accA[2][4], accB[2][4];
#pragma unroll
  for (int g = 0; g < 4; ++g) { accA[0][g] = bv[g]; accA[1][g] = bv[g]; }
#pragma unroll
  for (int g = 0; g < 4; ++g) {
    accA[0][g] = __builtin_amdgcn_mfma_f32_16x16x32_bf16(Wf[g][0], Xf0, accA[0][g], 0, 0, 0);
    accA[0][g] = __builtin_amdgcn_mfma_f32_16x16x32_bf16(Wf[g][1], Xf1, accA[0][g], 0, 0, 0);
    accA[1][g] = __builtin_amdgcn_mfma_f32_16x16x32_bf16(Wf[g][0], Xf2, accA[1][g], 0, 0, 0);
    accA[1][g] = __builtin_amdgcn_mfma_f32_16x16x32_bf16(Wf[g][1], Xf3, accA[1][g], 0, 0, 0);
  }

  const float NL2E = -1.44269504f;  // -log2(e)
  const float T2L2E = 2.88539008f;  // 2*log2(e)

  // one period: AC = gates(T) accumulator (already bias+X-part), AN = next-period acc.
  // RB/WB = read/write H buffer index. DO_H: do H-part MFMAs. DO_NEXT: prefetch X(T+1)
  // + init AN with bias + X-part MFMAs for T+1 (interleaves with epilogue).
#define PERIOD(T, AC, AN, RB, WB, DO_H, DO_NEXT)                                                      \
  do {                                                                                                \
    if (DO_NEXT) {                                                                                    \
      const size_t toff_ = (size_t)((T) + 1) * N * 64;                                                \
      Xf0 = *(const bf16x8*)(Xrow0 + toff_);                                                          \
      Xf1 = *(const bf16x8*)(Xrow0 + toff_ + 32);                                                     \
      Xf2 = *(const bf16x8*)(Xrow1 + toff_);                                                          \
      Xf3 = *(const bf16x8*)(Xrow1 + toff_ + 32);                                                     \
    }                                                                                                 \
    if (DO_H) {                                                                                       \
      _Pragma("unroll") for (int ks = 0; ks < 4; ++ks) {                                              \
        bf16x8 B0 = *(const bf16x8*)(&Hs[RB][(c0) * 256 + (((4 * ks + q) ^ swz) << 4)]);              \
        bf16x8 B1 = *(const bf16x8*)(&Hs[RB][(16 + c0) * 256 + (((4 * ks + q) ^ swz) << 4)]);         \
        _Pragma("unroll") for (int g = 0; g < 4; ++g) {                                               \
          AC[0][g] = __builtin_amdgcn_mfma_f32_16x16x32_bf16(Wf[g][ks + 2], B0, AC[0][g], 0, 0, 0);   \
          AC[1][g] = __builtin_amdgcn_mfma_f32_16x16x32_bf16(Wf[g][ks + 2], B1, AC[1][g], 0, 0, 0);   \
        }                                                                                             \
      }                                                                                               \
    }                                                                                                 \
    const float pt_ = probs[T];                                                                       \
    _Pragma("unroll") for (int rt = 0; rt < 2; ++rt) {                                                \
      bf16x4 hv_;                                                                                     \
      _Pragma("unroll") for (int r = 0; r < 4; ++r) {                                                 \
        float pI = AC[rt][0][r], pF = AC[rt][1][r], pC = AC[rt][2][r], pO = AC[rt][3][r];             \
        float I_ = __builtin_amdgcn_rcpf(1.0f + __builtin_amdgcn_exp2f(pI * NL2E));                   \
        float F_ = __builtin_amdgcn_rcpf(1.0f + __builtin_amdgcn_exp2f(pF * NL2E));                   \
        float Ct_ = fmaf(-2.0f, __builtin_amdgcn_rcpf(1.0f + __builtin_amdgcn_exp2f(pC * T2L2E)), 1.0f); \
        float O_ = __builtin_amdgcn_rcpf(1.0f + __builtin_amdgcn_exp2f(pO * NL2E));                   \
        float Cn_ = fmaf(F_, Cst[rt][r], I_ * Ct_);                                                   \
        Cst[rt][r] = Cn_;                                                                             \
        float tC_ = fmaf(-2.0f, __builtin_amdgcn_rcpf(1.0f + __builtin_amdgcn_exp2f(Cn_ * T2L2E)), 1.0f); \
        float Hn_ = O_ * tC_;                                                                         \
        Ha[rt][r] = fmaf(pt_, Hn_, Ha[rt][r]);                                                        \
        hv_[r] = (bf16_t)Hn_;                                                                         \
      }                                                                                               \
      *(bf16x4*)(&Hs[WB][(rt * 16 + c0) * 256 + (((2 * w + (q >> 1)) ^ swz) << 4) + ((q & 1) * 8)]) = hv_; \
    }                                                                                                 \
    if (DO_NEXT) {                                                                                    \
      _Pragma("unroll") for (int g = 0; g < 4; ++g) { AN[0][g] = bv[g]; AN[1][g] = bv[g]; }           \
      _Pragma("unroll") for (int g = 0; g < 4; ++g) {                                                 \
        AN[0][g] = __builtin_amdgcn_mfma_f32_16x16x32_bf16(Wf[g][0], Xf0, AN[0][g], 0, 0, 0);         \
        AN[0][g] = __builtin_amdgcn_mfma_f32_16x16x32_bf16(Wf[g][1], Xf1, AN[0][g], 0, 0, 0);         \
        AN[1][g] = __builtin_amdgcn_mfma_f32_16x16x32_bf16(Wf[g][0], Xf2, AN[1][g], 0, 0, 0);         \
        AN[1][g] = __builtin_amdgcn_mfma_f32_16x16x32_bf16(Wf[g][1], Xf3, AN[1][g], 0, 0, 0);         \
      }                                                                                               \
    }                                                                                                 \
    __syncthreads();                                                                                  \
  } while (0)

  // t even: reads Hs[1], writes Hs[0]; t odd: reads Hs[0], writes Hs[1].
  // Period 0: H(-1)=0 -> skip H-part (accA already = bias + X-part(0)); no zero-init needed.
  PERIOD(0, accA, accB, 1, 0, 0, 1);
  for (int tt = 1; tt <= 9; tt += 2) {
    PERIOD(tt, accB, accA, 0, 1, 1, 1);
    PERIOD(tt + 1, accA, accB, 1, 0, 1, 1);
  }
  PERIOD(11, accB, accA, 0, 1, 1, 0);
#undef PERIOD

#pragma unroll
  for (int rt = 0; rt < 2; ++rt) {
    int row = n0 + rt * 16 + c0;
    *(floatx4*)(out + (size_t)row * 128 + w * 16 + q * 4) = Ha[rt];
  }
}

// ---------------- host ----------------
extern "C" void kernel_launch(void* const* d_in, const int* in_sizes, int n_in,
                              void* d_out, int out_size, void* d_ws, size_t ws_size,
                              hipStream_t stream) {
  const float* X = (const float*)d_in[0];
  const int* ei = (const int*)d_in[1];
  const float* ew = (const float*)d_in[2];
  const float* att = (const float*)d_in[3];
  const float* Wxi = (const float*)d_in[4];
  const float* bxi = (const float*)d_in[5];
  const float* Whi = (const float*)d_in[6];
  const float* bhi = (const float*)d_in[7];
  const float* Wxf = (const float*)d_in[8];
  const float* bxf = (const float*)d_in[9];
  const float* Whf = (const float*)d_in[10];
  const float* bhf = (const float*)d_in[11];
  const float* Wxc = (const float*)d_in[12];
  const float* bxc = (const float*)d_in[13];
  const float* Whc = (const float*)d_in[14];
  const float* bhc = (const float*)d_in[15];
  const float* Wxo = (const float*)d_in[16];
  const float* bxo = (const float*)d_in[17];
  const float* Who = (const float*)d_in[18];
  const float* bho = (const float*)d_in[19];
  float* out = (float*)d_out;

  const int N = in_sizes[0] / XROW;  // 40000
  const int E = in_sizes[2];         // 640000

  char* base = (char*)d_ws;
  size_t off = 0;
  auto carve = [&](size_t bytes) {
    char* r = base + off;
    off += (bytes + 255) & ~(size_t)255;
    return (void*)r;
  };
  float* deg = (float*)carve((size_t)N * 4);  // becomes dinv in-place
  int* counts = (int*)carve((size_t)N * 4);
  int* offs = (int*)carve((size_t)(N + 1) * 4);
  int* cursor = (int*)carve((size_t)(N + 1) * 4);
  int* csr_src = (int*)carve((size_t)E * 4);
  float* csr_nrm = (float*)carve((size_t)E * 4);
  bf16_t* WbT = (bf16_t*)carve((size_t)512 * 192 * 2);
  float* bcomb = (float*)carve(512 * 4);
  float* probs = (float*)carve(64);
  int* bsum = (int*)carve(64 * 4);
  int* bbase = (int*)carve(68 * 4);
  bf16_t* Xagg = (bf16_t*)carve((size_t)PERIODSq * N * 64 * 2);
  bf16_t* Xb = (bf16_t*)carve((size_t)N * XROW * 2);
  const bool use_bf16 = (off <= ws_size);  // fall back to fp32 gather if ws too small

  k_init<<<(N + 255) / 256, 256, 0, stream>>>(deg, counts, N);
  k_accum<<<(E + 255) / 256, 256, 0, stream>>>(ei, ew, deg, counts, E);
  k_dinv<<<(N + 255) / 256, 256, 0, stream>>>(deg, N);
  const int nb = (N + 1023) >> 10;
  if (nb <= 64) {
    k_scanA<<<nb, 256, 0, stream>>>(counts, bsum, N);
    k_scanB<<<1, 64, 0, stream>>>(bsum, bbase, nb);
    k_scanC<<<nb, 256, 0, stream>>>(counts, bbase, offs, cursor, N, nb);
  } else {
    k_scan<<<1, 1024, 0, stream>>>(counts, offs, cursor, N);
  }
  k_scatter<<<(E + 255) / 256, 256, 0, stream>>>(ei, ew, deg, cursor, csr_src, csr_nrm, E);
  k_prew<<<(512 * 192 + 512 + 1 + 255) / 256, 256, 0, stream>>>(
      Wxi, Whi, Wxf, Whf, Wxc, Whc, Wxo, Who,
      bxi, bhi, bxf, bhf, bxc, bhc, bxo, bho, att, WbT, bcomb, probs);

  if (use_bf16) {
    k_xpose<<<N, 192, 0, stream>>>(X, Xb);
    k_agg2<<<N / 4, 256, 0, stream>>>(Xb, csr_src, csr_nrm, offs, deg, Xagg, N);
  } else {
    k_agg<<<N, 256, 0, stream>>>(X, csr_src, csr_nrm, offs, deg, Xagg, N);
  }

  k_gate_all<<<N / 32, 512, 0, stream>>>(Xagg, WbT, bcomb, probs, out, N);
}